// Round 9
// baseline (138.563 us; speedup 1.0000x reference)
//
#include <hip/hip_runtime.h>

#define SE_C   256
#define SE_B   16
#define SE_HW  16384   // 128*128
#define NPLANE (SE_B * SE_C)

typedef float fx4 __attribute__((ext_vector_type(4)));   // native vector for nt builtins

// ---------------- Kernel 1: global average pool per (b,c) plane ----------------
// Plain (caching) loads: incidental L3 retention from this pass partially feeds
// the scale pass's re-read (R7: FETCH 131/268 MB). No atomics (R7 lesson).
__global__ __launch_bounds__(256) void se_pool(const float* __restrict__ U,
                                               float* __restrict__ z) {
    const int plane = blockIdx.x;                       // 0 .. B*C-1
    const fx4* Up = (const fx4*)(U + (size_t)plane * SE_HW);
    const int t = threadIdx.x;

    float sum = 0.f;
    #pragma unroll
    for (int k = 0; k < 16; ++k) {                      // 16 * 256 * 4 = 16384 floats
        fx4 v = Up[t + k * 256];
        sum += (v.x + v.y) + (v.z + v.w);
    }
    // wave (64-lane) shuffle reduce
    #pragma unroll
    for (int off = 32; off > 0; off >>= 1)
        sum += __shfl_down(sum, off, 64);

    __shared__ float wsum[4];
    const int lane = t & 63, wid = t >> 6;
    if (lane == 0) wsum[wid] = sum;
    __syncthreads();
    if (t == 0) {
        float tot = (wsum[0] + wsum[1]) + (wsum[2] + wsum[3]);
        z[plane] = tot * (1.0f / SE_HW);
    }
}

// ---------------- Kernel 2: squeeze (relu) -> excite (sigmoid) ----------------
__global__ __launch_bounds__(256) void se_fc(const float* __restrict__ z,
                                             const float* __restrict__ w_sq,  // [C/2, C]
                                             const float* __restrict__ w_ex,  // [C, C/2]
                                             float* __restrict__ s) {
    const int b = blockIdx.x;
    const int t = threadIdx.x;

    __shared__ float zb[SE_C];
    __shared__ float h[SE_C / 2];

    zb[t] = z[b * SE_C + t];
    __syncthreads();

    if (t < SE_C / 2) {
        const float* wr = w_sq + t * SE_C;
        float acc = 0.f;
        #pragma unroll 8
        for (int c = 0; c < SE_C; ++c) acc = fmaf(wr[c], zb[c], acc);
        h[t] = fmaxf(acc, 0.f);
    }
    __syncthreads();

    {
        const float* wr = w_ex + t * (SE_C / 2);
        float acc = 0.f;
        #pragma unroll 8
        for (int c = 0; c < SE_C / 2; ++c) acc = fmaf(wr[c], h[c], acc);
        s[b * SE_C + t] = 1.0f / (1.0f + expf(-acc));
    }
}

// ---------------- Kernel 3: out = U * s[plane], read-burst then write-burst ----
// All 16 fx4 loaded first (nt: U is dead after this read, don't allocate),
// single waitcnt, then 16 nt-stores (non-allocating, verified R5). Maximizes
// outstanding reads per wave instead of dependent load->store pairs.
__global__ __launch_bounds__(256) void se_scale(const float* __restrict__ U,
                                                const float* __restrict__ s,
                                                float* __restrict__ out) {
    const int plane = blockIdx.x;
    const float g = s[plane];                            // uniform scalar per block
    const fx4* Up = (const fx4*)(U + (size_t)plane * SE_HW);
    fx4* Op = (fx4*)(out + (size_t)plane * SE_HW);
    const int t = threadIdx.x;

    fx4 v[16];
    #pragma unroll
    for (int k = 0; k < 16; ++k)
        v[k] = __builtin_nontemporal_load(Up + t + k * 256);
    #pragma unroll
    for (int k = 0; k < 16; ++k) {
        fx4 w = v[k] * g;
        __builtin_nontemporal_store(w, Op + t + k * 256);
    }
}

extern "C" void kernel_launch(void* const* d_in, const int* in_sizes, int n_in,
                              void* d_out, int out_size, void* d_ws, size_t ws_size,
                              hipStream_t stream) {
    const float* U    = (const float*)d_in[0];
    const float* w_sq = (const float*)d_in[1];
    const float* w_ex = (const float*)d_in[2];
    float* out = (float*)d_out;

    float* z = (float*)d_ws;             // [4096]
    float* s = z + NPLANE;               // [4096]

    se_pool <<<NPLANE, 256, 0, stream>>>(U, z);
    se_fc   <<<SE_B,   256, 0, stream>>>(z, w_sq, w_ex, s);
    se_scale<<<NPLANE, 256, 0, stream>>>(U, s, out);
}

// Round 10
// 135.802 us; speedup vs baseline: 1.0203x; 1.0203x over previous
//
#include <hip/hip_runtime.h>

#define SE_C   256
#define SE_B   16
#define SE_HW  16384   // 128*128
#define NPLANE (SE_B * SE_C)

typedef float fx4 __attribute__((ext_vector_type(4)));   // native vector for nt builtins

// ---------------- Kernel 1: global average pool per (b,c) plane ----------------
// Plain (caching) loads: L3 retention from this pass partially feeds the scale
// pass's re-read (R7: FETCH 131/268 MB => ~50% L3-resident). No atomics (R7).
__global__ __launch_bounds__(256) void se_pool(const float* __restrict__ U,
                                               float* __restrict__ z) {
    const int plane = blockIdx.x;                       // 0 .. B*C-1
    const fx4* Up = (const fx4*)(U + (size_t)plane * SE_HW);
    const int t = threadIdx.x;

    float sum = 0.f;
    #pragma unroll
    for (int k = 0; k < 16; ++k) {                      // 16 * 256 * 4 = 16384 floats
        fx4 v = Up[t + k * 256];
        sum += (v.x + v.y) + (v.z + v.w);
    }
    // wave (64-lane) shuffle reduce
    #pragma unroll
    for (int off = 32; off > 0; off >>= 1)
        sum += __shfl_down(sum, off, 64);

    __shared__ float wsum[4];
    const int lane = t & 63, wid = t >> 6;
    if (lane == 0) wsum[wid] = sum;
    __syncthreads();
    if (t == 0) {
        float tot = (wsum[0] + wsum[1]) + (wsum[2] + wsum[3]);
        z[plane] = tot * (1.0f / SE_HW);
    }
}

// ---------------- Kernel 2: squeeze (relu) -> excite (sigmoid) ----------------
__global__ __launch_bounds__(256) void se_fc(const float* __restrict__ z,
                                             const float* __restrict__ w_sq,  // [C/2, C]
                                             const float* __restrict__ w_ex,  // [C, C/2]
                                             float* __restrict__ s) {
    const int b = blockIdx.x;
    const int t = threadIdx.x;

    __shared__ float zb[SE_C];
    __shared__ float h[SE_C / 2];

    zb[t] = z[b * SE_C + t];
    __syncthreads();

    if (t < SE_C / 2) {
        const float* wr = w_sq + t * SE_C;
        float acc = 0.f;
        #pragma unroll 8
        for (int c = 0; c < SE_C; ++c) acc = fmaf(wr[c], zb[c], acc);
        h[t] = fmaxf(acc, 0.f);
    }
    __syncthreads();

    {
        const float* wr = w_ex + t * (SE_C / 2);
        float acc = 0.f;
        #pragma unroll 8
        for (int c = 0; c < SE_C / 2; ++c) acc = fmaf(wr[c], h[c], acc);
        s[b * SE_C + t] = 1.0f / (1.0f + expf(-acc));
    }
}

// ---------------- Kernel 3: out = U * s[plane] -------------------------------
// Read-burst with PLAIN loads (keep L3 partial hits; R9 showed nt-load costs
// ~3 us), then nt-store burst (non-allocating, verified R5).
__global__ __launch_bounds__(256) void se_scale(const float* __restrict__ U,
                                                const float* __restrict__ s,
                                                float* __restrict__ out) {
    const int plane = blockIdx.x;
    const float g = s[plane];                            // uniform scalar per block
    const fx4* Up = (const fx4*)(U + (size_t)plane * SE_HW);
    fx4* Op = (fx4*)(out + (size_t)plane * SE_HW);
    const int t = threadIdx.x;

    fx4 v[16];
    #pragma unroll
    for (int k = 0; k < 16; ++k)
        v[k] = Up[t + k * 256];                          // plain caching loads
    #pragma unroll
    for (int k = 0; k < 16; ++k) {
        fx4 w = v[k] * g;
        __builtin_nontemporal_store(w, Op + t + k * 256);
    }
}

extern "C" void kernel_launch(void* const* d_in, const int* in_sizes, int n_in,
                              void* d_out, int out_size, void* d_ws, size_t ws_size,
                              hipStream_t stream) {
    const float* U    = (const float*)d_in[0];
    const float* w_sq = (const float*)d_in[1];
    const float* w_ex = (const float*)d_in[2];
    float* out = (float*)d_out;

    float* z = (float*)d_ws;             // [4096]
    float* s = z + NPLANE;               // [4096]

    se_pool <<<NPLANE, 256, 0, stream>>>(U, z);
    se_fc   <<<SE_B,   256, 0, stream>>>(z, w_sq, w_ex, s);
    se_scale<<<NPLANE, 256, 0, stream>>>(U, s, out);
}